// Round 3
// baseline (8915.694 us; speedup 1.0000x reference)
//
#include <hip/hip_runtime.h>
#include <hip/hip_bf16.h>

typedef float f4 __attribute__((ext_vector_type(4)));

#define FIN 512
#define FHID 128
#define FOUT 64

// ---------------- degree count (in-degree over real edges; +1 self-loop folded into dinv) ----
__global__ void k_deg(const int* __restrict__ dst, int E, unsigned* __restrict__ cnt) {
    int i = blockIdx.x * blockDim.x + threadIdx.x;
    if (i < E) atomicAdd(&cnt[dst[i]], 1u);
}

__global__ void k_dinv(const unsigned* __restrict__ cnt, float* __restrict__ dinv, int n) {
    int i = blockIdx.x * blockDim.x + threadIdx.x;
    if (i < n) dinv[i] = rsqrtf((float)cnt[i] + 1.0f);
}

// ---------------- GEMM1: C[M,128] = A[M,512] @ W[512,128] ----------------
// 128x128 tile, 256 threads, 8x8 per-thread register tile, BK=16.
__global__ __launch_bounds__(256) void k_gemm1(const float* __restrict__ A,
                                               const float* __restrict__ W,
                                               float* __restrict__ C, int M) {
    __shared__ __align__(16) float As[16][132];  // transposed: As[k][m]
    __shared__ __align__(16) float Bs[16][132];  // Bs[k][n]
    const int tid = threadIdx.x;
    const int tx = tid & 15, ty = tid >> 4;
    const int m0 = blockIdx.x * 128;

    f4 acc[8][2];
    #pragma unroll
    for (int i = 0; i < 8; ++i) { acc[i][0] = 0.f; acc[i][1] = 0.f; }

    for (int k0 = 0; k0 < FIN; k0 += 16) {
        // stage A tile: 128 rows x 16 k (2 float4 per thread), transposed into LDS
        #pragma unroll
        for (int i = 0; i < 2; ++i) {
            int q = tid * 2 + i;          // 0..511
            int row = q >> 2;             // 0..127
            int kq = (q & 3) * 4;         // 0,4,8,12
            int gr = m0 + row;
            f4 v = {0.f, 0.f, 0.f, 0.f};
            if (gr < M) v = *(const f4*)&A[(size_t)gr * FIN + k0 + kq];
            #pragma unroll
            for (int j = 0; j < 4; ++j) As[kq + j][row] = v[j];
        }
        // stage B tile: 16 k x 128 cols (2 float4 per thread)
        #pragma unroll
        for (int i = 0; i < 2; ++i) {
            int s = tid + i * 256;        // 0..511 float4 slots
            int kr = s >> 5, c4 = (s & 31) * 4;
            *(f4*)&Bs[kr][c4] = *(const f4*)&W[(size_t)(k0 + kr) * FHID + c4];
        }
        __syncthreads();
        #pragma unroll
        for (int kk = 0; kk < 16; ++kk) {
            f4 a0 = *(const f4*)&As[kk][ty * 8];
            f4 a1 = *(const f4*)&As[kk][ty * 8 + 4];
            f4 b0 = *(const f4*)&Bs[kk][tx * 4];
            f4 b1 = *(const f4*)&Bs[kk][64 + tx * 4];
            #pragma unroll
            for (int i = 0; i < 4; ++i) {
                acc[i][0]     += a0[i] * b0;  acc[i][1]     += a0[i] * b1;
                acc[i + 4][0] += a1[i] * b0;  acc[i + 4][1] += a1[i] * b1;
            }
        }
        __syncthreads();
    }
    #pragma unroll
    for (int i = 0; i < 8; ++i) {
        int gr = m0 + ty * 8 + i;
        if (gr < M) {
            *(f4*)&C[(size_t)gr * FHID + tx * 4]      = acc[i][0];
            *(f4*)&C[(size_t)gr * FHID + 64 + tx * 4] = acc[i][1];
        }
    }
}

// ---------------- GEMM2: C[M,64] = relu(A[M,128]+b1) @ W[128,64] ----------------
__global__ __launch_bounds__(256) void k_gemm2(const float* __restrict__ A,
                                               const float* __restrict__ W,
                                               const float* __restrict__ bias,
                                               float* __restrict__ C, int M) {
    __shared__ __align__(16) float As[16][132];
    __shared__ __align__(16) float Bs[16][68];
    const int tid = threadIdx.x;
    const int tx = tid & 15, ty = tid >> 4;
    const int m0 = blockIdx.x * 128;

    f4 acc[8];
    #pragma unroll
    for (int i = 0; i < 8; ++i) acc[i] = 0.f;

    for (int k0 = 0; k0 < FHID; k0 += 16) {
        #pragma unroll
        for (int i = 0; i < 2; ++i) {
            int q = tid * 2 + i;
            int row = q >> 2;
            int kq = (q & 3) * 4;
            int gr = m0 + row;
            f4 v = {0.f, 0.f, 0.f, 0.f};
            if (gr < M) v = *(const f4*)&A[(size_t)gr * FHID + k0 + kq];
            f4 bb = *(const f4*)&bias[k0 + kq];
            #pragma unroll
            for (int j = 0; j < 4; ++j) As[kq + j][row] = fmaxf(v[j] + bb[j], 0.f);
        }
        {
            int kr = tid >> 4, c4 = (tid & 15) * 4;  // 16 k-rows x 64 cols
            *(f4*)&Bs[kr][c4] = *(const f4*)&W[(size_t)(k0 + kr) * FOUT + c4];
        }
        __syncthreads();
        #pragma unroll
        for (int kk = 0; kk < 16; ++kk) {
            f4 a0 = *(const f4*)&As[kk][ty * 8];
            f4 a1 = *(const f4*)&As[kk][ty * 8 + 4];
            f4 b0 = *(const f4*)&Bs[kk][tx * 4];
            #pragma unroll
            for (int i = 0; i < 4; ++i) {
                acc[i]     += a0[i] * b0;
                acc[i + 4] += a1[i] * b0;
            }
        }
        __syncthreads();
    }
    #pragma unroll
    for (int i = 0; i < 8; ++i) {
        int gr = m0 + ty * 8 + i;
        if (gr < M) *(f4*)&C[(size_t)gr * FOUT + tx * 4] = acc[i];
    }
}

// ---------------- edge scatter: agg[d] += xw[s] * dinv[s]*dinv[d], + self-loops ----
template <int F, int LOGFQ>
__global__ void k_scatter(const int* __restrict__ ei, int E, int n,
                          const float* __restrict__ xw, const float* __restrict__ dinv,
                          float* __restrict__ agg) {
    const int FQ = F / 4;
    const int total = (E + n) * FQ;
    const int stride = gridDim.x * blockDim.x;
    for (int t = blockIdx.x * blockDim.x + threadIdx.x; t < total; t += stride) {
        int item = t >> LOGFQ;
        int fq = t & (FQ - 1);
        int s, d;
        if (item < E) {
            s = ei[item];
            d = ei[E + item];
        } else {
            s = d = item - E;
        }
        float w = dinv[s] * dinv[d];
        f4 v = *(const f4*)&xw[(size_t)s * F + fq * 4];
        float* p = &agg[(size_t)d * F + fq * 4];
        unsafeAtomicAdd(p + 0, v[0] * w);
        unsafeAtomicAdd(p + 1, v[1] * w);
        unsafeAtomicAdd(p + 2, v[2] * w);
        unsafeAtomicAdd(p + 3, v[3] * w);
    }
}

// ---------------- fused +b2 and log_softmax over 64 features, in place ----------------
__global__ void k_lsm(float* __restrict__ out, const float* __restrict__ b2, int n) {
    int gtid = blockIdx.x * blockDim.x + threadIdx.x;
    int row = gtid >> 6;
    int lane = threadIdx.x & 63;
    if (row >= n) return;
    float v = out[(size_t)row * 64 + lane] + b2[lane];
    float m = v;
    #pragma unroll
    for (int o = 32; o; o >>= 1) m = fmaxf(m, __shfl_xor(m, o));
    float e = expf(v - m);
    #pragma unroll
    for (int o = 32; o; o >>= 1) e += __shfl_xor(e, o);
    out[(size_t)row * 64 + lane] = v - m - logf(e);
}

extern "C" void kernel_launch(void* const* d_in, const int* in_sizes, int n_in,
                              void* d_out, int out_size, void* d_ws, size_t ws_size,
                              hipStream_t stream) {
    const float* x  = (const float*)d_in[0];
    const float* W1 = (const float*)d_in[1];
    const float* b1 = (const float*)d_in[2];
    const float* W2 = (const float*)d_in[3];
    const float* b2 = (const float*)d_in[4];
    const int* ei   = (const int*)d_in[5];   // int32! (JAX x64 disabled)
    const int n = in_sizes[0] / FIN;     // 100000
    const int E = in_sizes[5] / 2;       // 3200000
    float* out = (float*)d_out;

    char* ws = (char*)d_ws;
    size_t off = 0;
    auto alloc = [&](size_t bytes) { void* p = ws + off; off = (off + bytes + 255) & ~(size_t)255; return p; };
    unsigned* cnt = (unsigned*)alloc((size_t)n * 4);
    float* dinv   = (float*)alloc((size_t)n * 4);
    float* bufA   = (float*)alloc((size_t)n * FHID * 4);   // xw1, later reused as xw2
    float* agg1   = (float*)alloc((size_t)n * FHID * 4);
    float* xw1 = bufA;
    float* xw2 = bufA;   // xw1 dead once scatter1 completes

    hipMemsetAsync(cnt, 0, (size_t)n * 4, stream);
    hipMemsetAsync(agg1, 0, (size_t)n * FHID * 4, stream);
    hipMemsetAsync(d_out, 0, (size_t)n * FOUT * 4, stream);

    k_deg<<<(E + 255) / 256, 256, 0, stream>>>(ei + E, E, cnt);
    k_dinv<<<(n + 255) / 256, 256, 0, stream>>>(cnt, dinv, n);
    k_gemm1<<<(n + 127) / 128, 256, 0, stream>>>(x, W1, xw1, n);
    k_scatter<128, 5><<<4096, 256, 0, stream>>>(ei, E, n, xw1, dinv, agg1);
    k_gemm2<<<(n + 127) / 128, 256, 0, stream>>>(agg1, W2, b1, xw2, n);
    k_scatter<64, 4><<<4096, 256, 0, stream>>>(ei, E, n, xw2, dinv, out);
    k_lsm<<<(n + 3) / 4, 256, 0, stream>>>(out, b2, n);
}

// Round 6
// 1272.663 us; speedup vs baseline: 7.0055x; 7.0055x over previous
//
#include <hip/hip_runtime.h>
#include <hip/hip_bf16.h>

typedef float f4 __attribute__((ext_vector_type(4)));
typedef float f2 __attribute__((ext_vector_type(2)));

#define FIN 512
#define FHID 128
#define FOUT 64
#define SCAN_CHUNK 2048

// ---------------- degree count (in-degree over real edges; +1 self-loop folded into dinv) ----
__global__ void k_deg(const int* __restrict__ dst, int E, unsigned* __restrict__ cnt) {
    int i = blockIdx.x * blockDim.x + threadIdx.x;
    if (i < E) atomicAdd(&cnt[dst[i]], 1u);
}

__global__ void k_dinv(const unsigned* __restrict__ cnt, float* __restrict__ dinv, int n) {
    int i = blockIdx.x * blockDim.x + threadIdx.x;
    if (i < n) dinv[i] = rsqrtf((float)cnt[i] + 1.0f);
}

// ---------------- CSR build: exclusive scan of cnt -> rowptr, then fill ----------------
__global__ __launch_bounds__(256) void k_scan_local(const unsigned* __restrict__ cnt, int n,
                                                    unsigned* __restrict__ pre,
                                                    unsigned* __restrict__ bsum) {
    __shared__ unsigned tsum[256];
    int base = blockIdx.x * SCAN_CHUNK + threadIdx.x * 8;
    unsigned v[8];
    unsigned s = 0;
    #pragma unroll
    for (int i = 0; i < 8; ++i) v[i] = (base + i < n) ? cnt[base + i] : 0u;
    #pragma unroll
    for (int i = 0; i < 8; ++i) { unsigned t = v[i]; v[i] = s; s += t; }
    tsum[threadIdx.x] = s;
    __syncthreads();
    for (int off = 1; off < 256; off <<= 1) {
        unsigned add = (threadIdx.x >= (unsigned)off) ? tsum[threadIdx.x - off] : 0u;
        __syncthreads();
        tsum[threadIdx.x] += add;
        __syncthreads();
    }
    unsigned prefix = (threadIdx.x == 0) ? 0u : tsum[threadIdx.x - 1];
    #pragma unroll
    for (int i = 0; i < 8; ++i)
        if (base + i < n) pre[base + i] = v[i] + prefix;
    if (threadIdx.x == 255) bsum[blockIdx.x] = tsum[255];
}

__global__ void k_scan_bsum(unsigned* __restrict__ bsum, int B) {
    if (threadIdx.x == 0 && blockIdx.x == 0) {
        unsigned s = 0;
        for (int i = 0; i < B; ++i) { unsigned t = bsum[i]; bsum[i] = s; s += t; }
    }
}

__global__ __launch_bounds__(256) void k_scan_add(unsigned* __restrict__ pre,
                                                  unsigned* __restrict__ cursor,
                                                  const unsigned* __restrict__ bsum, int n, int E) {
    int base = blockIdx.x * SCAN_CHUNK + threadIdx.x * 8;
    unsigned b = bsum[blockIdx.x];
    #pragma unroll
    for (int k = 0; k < 8; ++k) {
        int idx = base + k;
        if (idx < n) { unsigned r = pre[idx] + b; pre[idx] = r; cursor[idx] = r; }
    }
    if (blockIdx.x == 0 && threadIdx.x == 0) pre[n] = (unsigned)E;
}

__global__ void k_fill(const int* __restrict__ src, const int* __restrict__ dst, int E,
                       unsigned* __restrict__ cursor, int* __restrict__ csr) {
    int i = blockIdx.x * blockDim.x + threadIdx.x;
    if (i < E) {
        unsigned p = atomicAdd(&cursor[dst[i]], 1u);
        csr[p] = src[i];
    }
}

// ---------------- GEMM1: C[M,128] = (A[M,512] @ W[512,128]) * dinv[row] ----------------
__global__ __launch_bounds__(256) void k_gemm1(const float* __restrict__ A,
                                               const float* __restrict__ W,
                                               const float* __restrict__ dinv,
                                               float* __restrict__ C, int M) {
    __shared__ __align__(16) float As[16][132];  // transposed: As[k][m]
    __shared__ __align__(16) float Bs[16][132];  // Bs[k][n]
    const int tid = threadIdx.x;
    const int tx = tid & 15, ty = tid >> 4;
    const int m0 = blockIdx.x * 128;

    f4 acc[8][2];
    #pragma unroll
    for (int i = 0; i < 8; ++i) { acc[i][0] = 0.f; acc[i][1] = 0.f; }

    for (int k0 = 0; k0 < FIN; k0 += 16) {
        #pragma unroll
        for (int i = 0; i < 2; ++i) {
            int q = tid * 2 + i;
            int row = q >> 2;
            int kq = (q & 3) * 4;
            int gr = m0 + row;
            f4 v = {0.f, 0.f, 0.f, 0.f};
            if (gr < M) v = *(const f4*)&A[(size_t)gr * FIN + k0 + kq];
            #pragma unroll
            for (int j = 0; j < 4; ++j) As[kq + j][row] = v[j];
        }
        #pragma unroll
        for (int i = 0; i < 2; ++i) {
            int s = tid + i * 256;
            int kr = s >> 5, c4 = (s & 31) * 4;
            *(f4*)&Bs[kr][c4] = *(const f4*)&W[(size_t)(k0 + kr) * FHID + c4];
        }
        __syncthreads();
        #pragma unroll
        for (int kk = 0; kk < 16; ++kk) {
            f4 a0 = *(const f4*)&As[kk][ty * 8];
            f4 a1 = *(const f4*)&As[kk][ty * 8 + 4];
            f4 b0 = *(const f4*)&Bs[kk][tx * 4];
            f4 b1 = *(const f4*)&Bs[kk][64 + tx * 4];
            #pragma unroll
            for (int i = 0; i < 4; ++i) {
                acc[i][0]     += a0[i] * b0;  acc[i][1]     += a0[i] * b1;
                acc[i + 4][0] += a1[i] * b0;  acc[i + 4][1] += a1[i] * b1;
            }
        }
        __syncthreads();
    }
    #pragma unroll
    for (int i = 0; i < 8; ++i) {
        int gr = m0 + ty * 8 + i;
        if (gr < M) {
            float sc = dinv[gr];
            *(f4*)&C[(size_t)gr * FHID + tx * 4]      = acc[i][0] * sc;
            *(f4*)&C[(size_t)gr * FHID + 64 + tx * 4] = acc[i][1] * sc;
        }
    }
}

// ---------------- GEMM2: C[M,64] = (relu(A[M,128]+b1) @ W[128,64]) * dinv[row] -------
__global__ __launch_bounds__(256) void k_gemm2(const float* __restrict__ A,
                                               const float* __restrict__ W,
                                               const float* __restrict__ bias,
                                               const float* __restrict__ dinv,
                                               float* __restrict__ C, int M) {
    __shared__ __align__(16) float As[16][132];
    __shared__ __align__(16) float Bs[16][68];
    const int tid = threadIdx.x;
    const int tx = tid & 15, ty = tid >> 4;
    const int m0 = blockIdx.x * 128;

    f4 acc[8];
    #pragma unroll
    for (int i = 0; i < 8; ++i) acc[i] = 0.f;

    for (int k0 = 0; k0 < FHID; k0 += 16) {
        #pragma unroll
        for (int i = 0; i < 2; ++i) {
            int q = tid * 2 + i;
            int row = q >> 2;
            int kq = (q & 3) * 4;
            int gr = m0 + row;
            f4 v = {0.f, 0.f, 0.f, 0.f};
            if (gr < M) v = *(const f4*)&A[(size_t)gr * FHID + k0 + kq];
            f4 bb = *(const f4*)&bias[k0 + kq];
            #pragma unroll
            for (int j = 0; j < 4; ++j) As[kq + j][row] = fmaxf(v[j] + bb[j], 0.f);
        }
        {
            int kr = tid >> 4, c4 = (tid & 15) * 4;
            *(f4*)&Bs[kr][c4] = *(const f4*)&W[(size_t)(k0 + kr) * FOUT + c4];
        }
        __syncthreads();
        #pragma unroll
        for (int kk = 0; kk < 16; ++kk) {
            f4 a0 = *(const f4*)&As[kk][ty * 8];
            f4 a1 = *(const f4*)&As[kk][ty * 8 + 4];
            f4 b0 = *(const f4*)&Bs[kk][tx * 4];
            #pragma unroll
            for (int i = 0; i < 4; ++i) {
                acc[i]     += a0[i] * b0;
                acc[i + 4] += a1[i] * b0;
            }
        }
        __syncthreads();
    }
    #pragma unroll
    for (int i = 0; i < 8; ++i) {
        int gr = m0 + ty * 8 + i;
        if (gr < M) {
            *(f4*)&C[(size_t)gr * FOUT + tx * 4] = acc[i] * dinv[gr];
        }
    }
}

// ---------------- gather1: agg[d] = dinv[d] * (sum_{s in N(d)} xws[s] + xws[d]), F=128 ----
// one 64-lane wave per destination row; lane covers features [2*lane, 2*lane+1]
__global__ __launch_bounds__(256) void k_gather1(const unsigned* __restrict__ rowptr,
                                                 const int* __restrict__ csr,
                                                 const float* __restrict__ xws,
                                                 const float* __restrict__ dinv,
                                                 float* __restrict__ agg, int n) {
    int d = (blockIdx.x * blockDim.x + threadIdx.x) >> 6;
    int lane = threadIdx.x & 63;
    if (d >= n) return;
    unsigned j0 = rowptr[d], j1 = rowptr[d + 1];
    f2 acc = *(const f2*)&xws[(size_t)d * FHID + lane * 2];  // self-loop
    unsigned j = j0;
    for (; j + 1 < j1; j += 2) {
        int s0 = csr[j], s1 = csr[j + 1];
        f2 v0 = *(const f2*)&xws[(size_t)s0 * FHID + lane * 2];
        f2 v1 = *(const f2*)&xws[(size_t)s1 * FHID + lane * 2];
        acc += v0;
        acc += v1;
    }
    if (j < j1) acc += *(const f2*)&xws[(size_t)csr[j] * FHID + lane * 2];
    *(f2*)&agg[(size_t)d * FHID + lane * 2] = acc * dinv[d];
}

// ---------------- gather2 + b2 + log_softmax fused, F=64: one wave per row --------------
__global__ __launch_bounds__(256) void k_gather2_lsm(const unsigned* __restrict__ rowptr,
                                                     const int* __restrict__ csr,
                                                     const float* __restrict__ xws,
                                                     const float* __restrict__ dinv,
                                                     const float* __restrict__ b2,
                                                     float* __restrict__ out, int n) {
    int d = (blockIdx.x * blockDim.x + threadIdx.x) >> 6;
    int lane = threadIdx.x & 63;
    if (d >= n) return;
    unsigned j0 = rowptr[d], j1 = rowptr[d + 1];
    float acc = xws[(size_t)d * FOUT + lane];  // self-loop
    unsigned j = j0;
    for (; j + 1 < j1; j += 2) {
        int s0 = csr[j], s1 = csr[j + 1];
        acc += xws[(size_t)s0 * FOUT + lane];
        acc += xws[(size_t)s1 * FOUT + lane];
    }
    if (j < j1) acc += xws[(size_t)csr[j] * FOUT + lane];
    float v = acc * dinv[d] + b2[lane];
    float m = v;
    #pragma unroll
    for (int o = 32; o; o >>= 1) m = fmaxf(m, __shfl_xor(m, o));
    float e = expf(v - m);
    #pragma unroll
    for (int o = 32; o; o >>= 1) e += __shfl_xor(e, o);
    out[(size_t)d * FOUT + lane] = v - m - logf(e);
}

// ---------------- fallback scatter: xw already carries dinv[src]; apply dinv[dst] only ----
template <int F, int LOGFQ>
__global__ void k_scatter_dst(const int* __restrict__ ei, int E, int n,
                              const float* __restrict__ xw, const float* __restrict__ dinv,
                              float* __restrict__ agg) {
    const int FQ = F / 4;
    const int total = (E + n) * FQ;
    const int stride = gridDim.x * blockDim.x;
    for (int t = blockIdx.x * blockDim.x + threadIdx.x; t < total; t += stride) {
        int item = t >> LOGFQ;
        int fq = t & (FQ - 1);
        int s, d;
        if (item < E) { s = ei[item]; d = ei[E + item]; }
        else { s = d = item - E; }
        float w = dinv[d];  // dinv[s] already folded into xw by the GEMM epilogue
        f4 v = *(const f4*)&xw[(size_t)s * F + fq * 4];
        float* p = &agg[(size_t)d * F + fq * 4];
        unsafeAtomicAdd(p + 0, v[0] * w);
        unsafeAtomicAdd(p + 1, v[1] * w);
        unsafeAtomicAdd(p + 2, v[2] * w);
        unsafeAtomicAdd(p + 3, v[3] * w);
    }
}

__global__ void k_lsm(float* __restrict__ out, const float* __restrict__ b2, int n) {
    int gtid = blockIdx.x * blockDim.x + threadIdx.x;
    int row = gtid >> 6;
    int lane = threadIdx.x & 63;
    if (row >= n) return;
    float v = out[(size_t)row * 64 + lane] + b2[lane];
    float m = v;
    #pragma unroll
    for (int o = 32; o; o >>= 1) m = fmaxf(m, __shfl_xor(m, o));
    float e = expf(v - m);
    #pragma unroll
    for (int o = 32; o; o >>= 1) e += __shfl_xor(e, o);
    out[(size_t)row * 64 + lane] = v - m - logf(e);
}

extern "C" void kernel_launch(void* const* d_in, const int* in_sizes, int n_in,
                              void* d_out, int out_size, void* d_ws, size_t ws_size,
                              hipStream_t stream) {
    const float* x  = (const float*)d_in[0];
    const float* W1 = (const float*)d_in[1];
    const float* b1 = (const float*)d_in[2];
    const float* W2 = (const float*)d_in[3];
    const float* b2 = (const float*)d_in[4];
    const int* ei   = (const int*)d_in[5];   // int32 (JAX x64 disabled)
    const int n = in_sizes[0] / FIN;     // 100000
    const int E = in_sizes[5] / 2;       // 3200000
    float* out = (float*)d_out;

    char* ws = (char*)d_ws;
    size_t off = 0;
    auto alloc = [&](size_t bytes) { void* p = ws + off; off = (off + bytes + 255) & ~(size_t)255; return p; };

    unsigned* cnt    = (unsigned*)alloc((size_t)n * 4);
    float* dinv      = (float*)alloc((size_t)n * 4);
    unsigned* rowptr = (unsigned*)alloc((size_t)(n + 1) * 4);
    unsigned* cursor = (unsigned*)alloc((size_t)n * 4);
    unsigned* bsum   = (unsigned*)alloc(256 * 4);
    int* csr         = (int*)alloc((size_t)E * 4);
    float* bufA      = (float*)alloc((size_t)n * FHID * 4);  // xws1, reused as xws2
    float* agg1      = (float*)alloc((size_t)n * FHID * 4);
    const size_t need_csr = off;

    hipMemsetAsync(cnt, 0, (size_t)n * 4, stream);
    k_deg<<<(E + 255) / 256, 256, 0, stream>>>(ei + E, E, cnt);
    k_dinv<<<(n + 255) / 256, 256, 0, stream>>>(cnt, dinv, n);

    if (ws_size >= need_csr) {
        // ---- CSR gather path ----
        const int SB = (n + SCAN_CHUNK - 1) / SCAN_CHUNK;  // 49
        k_scan_local<<<SB, 256, 0, stream>>>(cnt, n, rowptr, bsum);
        k_scan_bsum<<<1, 64, 0, stream>>>(bsum, SB);
        k_scan_add<<<SB, 256, 0, stream>>>(rowptr, cursor, bsum, n, E);
        k_fill<<<(E + 255) / 256, 256, 0, stream>>>(ei, ei + E, E, cursor, csr);

        k_gemm1<<<(n + 127) / 128, 256, 0, stream>>>(x, W1, dinv, bufA, n);
        k_gather1<<<(n + 3) / 4, 256, 0, stream>>>(rowptr, csr, bufA, dinv, agg1, n);
        k_gemm2<<<(n + 127) / 128, 256, 0, stream>>>(agg1, W2, b1, dinv, bufA, n);
        k_gather2_lsm<<<(n + 3) / 4, 256, 0, stream>>>(rowptr, csr, bufA, dinv, b2, out, n);
    } else {
        // ---- fallback: atomic-scatter path (needs only ~103 MB). dinv[src] is folded
        // into the GEMM epilogues; k_scatter_dst applies dinv[dst] only — correct for
        // edges AND self-loops (s==d: product dinv[d]^2 appears via fold + scatter). ----
        size_t off2 = 0;
        auto alloc2 = [&](size_t bytes) { void* p = ws + off2; off2 = (off2 + bytes + 255) & ~(size_t)255; return p; };
        (void)alloc2((size_t)n * 4);   // cnt (same slot as above)
        (void)alloc2((size_t)n * 4);   // dinv (same slot as above)
        float* bufA2 = (float*)alloc2((size_t)n * FHID * 4);
        float* agg2  = (float*)alloc2((size_t)n * FHID * 4);

        hipMemsetAsync(agg2, 0, (size_t)n * FHID * 4, stream);
        hipMemsetAsync(d_out, 0, (size_t)n * FOUT * 4, stream);
        k_gemm1<<<(n + 127) / 128, 256, 0, stream>>>(x, W1, dinv, bufA2, n);
        k_scatter_dst<FHID, 5><<<4096, 256, 0, stream>>>(ei, E, n, bufA2, dinv, agg2);
        k_gemm2<<<(n + 127) / 128, 256, 0, stream>>>(agg2, W2, b1, dinv, bufA2, n);
        k_scatter_dst<FOUT, 4><<<4096, 256, 0, stream>>>(ei, E, n, bufA2, dinv, out);
        k_lsm<<<(n + 3) / 4, 256, 0, stream>>>(out, b2, n);
    }
}